// Round 10
// baseline (131.253 us; speedup 1.0000x reference)
//
#include <hip/hip_runtime.h>

#define IN_DIM  4096
#define OUT_DIM 11008
#define NSUB    1376
#define KSQ     256
#define DSUB    8
#define BATCH   32

#define DTILE   8                    // subspaces per block
#define NTILE   64                   // output cols per block
#define KC      64                   // k per chunk
#define KSPLIT  8                    // k-blocks in grid; x2 wave-halves = 16 slices
#define KPB     (IN_DIM / KSPLIT)    // 512 k per block (256 per wave-half)
#define NCHUNK  4                    // chunks per wave (4 x 64 = 256 k)
#define NSLICE  16                   // slab k-slices (KSPLIT * 2)
#define NBLK    (OUT_DIM / NTILE)    // 172
#define NBLKP   176                  // padded: 8 XCDs * 22
#define NPX     (NBLKP / 8)          // 22 nblk per XCD
#define GRID_MAIN (NBLKP * KSPLIT)   // 1408 blocks of 512 threads

typedef unsigned short ushort_t;
typedef unsigned int   uint_t;
typedef unsigned char  uchar_t;
typedef __attribute__((ext_vector_type(8))) short bf16x8;
typedef __attribute__((ext_vector_type(4))) float f32x4;

// workspace layout (bytes)
#define VEC_N    (NSUB * KSQ * DSUB)              // 2818048 floats
#define XBF_OFF  (VEC_N * 2)                      // 5636096  : xbf (bf16 x)
#define IDXT_OFF (XBF_OFF + BATCH * IN_DIM * 2)   // 5898240  : idx8T [NSUB][IN_DIM] u8
#define SLAB_OFF (IDXT_OFF + NSUB * IN_DIM)       // 11534336 : f32 slabs [NSLICE][BATCH][OUT_DIM]
#define PREP_V   (VEC_N / 2)                      // 1409024 uints (2 bf16 each)
#define PREP_X   (BATCH * IN_DIM / 2)             // 65536
#define PREP_N   (PREP_V + PREP_X)                // 1474560 = 5760 * 256
#define PACK_BLK (PREP_N / 256)                   // 5760
#define IDXT_BLK ((IN_DIM / 128) * (NSUB / 32))   // 1376

__device__ __forceinline__ ushort_t f2bf(float f) {
    union { float f; uint_t u; } a; a.f = f;
    uint_t u = a.u;
    u += 0x7fffu + ((u >> 16) & 1u);   // round-to-nearest-even
    return (ushort_t)(u >> 16);
}

// opaque register fence on scalar components (128-bit ties unsupported)
__device__ __forceinline__ void pin4(uint4& x) {
    asm volatile("" : "+v"(x.x), "+v"(x.y), "+v"(x.z), "+v"(x.w));
}
__device__ __forceinline__ void pin1(uint_t& x) { asm volatile("" : "+v"(x)); }
__device__ __forceinline__ bf16x8 as_bf16x8(uint4 u) {
    union { uint4 u; bf16x8 v; } c; c.u = u; return c.v;
}

// ---- prep: bf16-pack codebook + x, AND transpose idx -> u8 [d][k] ---------
__global__ __launch_bounds__(256) void pq_prep(
    const float* __restrict__ x, const float* __restrict__ vecs,
    const int* __restrict__ idx,
    uint_t* __restrict__ vbf, uint_t* __restrict__ xbf,
    uchar_t* __restrict__ idx8T)
{
    __shared__ uchar_t sT[32][144];
    const int t = threadIdx.x;

    if (blockIdx.x < PACK_BLK) {
        int tid = blockIdx.x * 256 + t;
        if (tid < PREP_V) {
            float2 v = ((const float2*)vecs)[tid];
            vbf[tid] = (uint_t)f2bf(v.x) | ((uint_t)f2bf(v.y) << 16);
        } else {
            int i = tid - PREP_V;
            float2 v = ((const float2*)x)[i];
            xbf[i] = (uint_t)f2bf(v.x) | ((uint_t)f2bf(v.y) << 16);
        }
        return;
    }

    // idx transpose path
    const int bid = blockIdx.x - PACK_BLK;
    const int k0 = (bid & 31) * 128, d0 = (bid >> 5) * 32;
    #pragma unroll
    for (int p = 0; p < 16; ++p) {
        int f = p * 256 + t;           // 0..4095
        int kk = f >> 5, dd = f & 31;
        sT[dd][kk] = (uchar_t)idx[(size_t)(k0 + kk) * NSUB + d0 + dd];
    }
    __syncthreads();
    int dd = t >> 3, seg = t & 7;
    uint4 v = *(const uint4*)&sT[dd][seg * 16];
    *(uint4*)&idx8T[(size_t)(d0 + dd) * IN_DIM + k0 + seg * 16] = v;
}

// ---- main: 8-wave blocks, codebook shared across k-halves -----------------
//
// Block = 512 threads = 8 waves. Wave w owns subspace-pair (w&3) and k-half
// (w>>2): waves w and w+4 SHARE one 8 KB codebook slice in LDS (staged once
// by waves 0-3, one __syncthreads), halving LDS per wave vs the 4-wave
// version: 48 KB / 8 waves -> 3 blocks/CU = 24 waves/CU (was 16). The
// kernel is latency-bound with all pipes idle (R6: VALU<25%, Mfma 2%, HBM
// 8%, occupancy 35%) -- TLP is the binding resource this round attacks.
// XCD decode keeps all k-siblings of an nblk on one XCD's L2.
__global__ __launch_bounds__(512, 3) void pq_main(
    const ushort_t* __restrict__ xbfu, const uint4* __restrict__ vbf4,
    const uchar_t* __restrict__ idx8T, float* __restrict__ slab)
{
    __shared__ uint4  sV4[4 * 512];        // 32 KB: 4 subspace-pairs x 256 codewords
    __shared__ uint_t sW32[8 * 16 * 32];   // 16 KB: per-wave 16 rows x 64 k (swizzled)

    const int id  = blockIdx.x;
    const int xcd = id & 7;
    const int s   = id >> 3;               // 0..175
    const int nblk = xcd * NPX + (s % NPX);
    const int kblk = s / NPX;              // 0..7
    if (nblk >= NBLK) return;              // uniform per block (no barrier hazard)

    const int t    = threadIdx.x;
    const int w    = t >> 6;               // 0..7
    const int wp   = w & 3;                // subspace-pair within block
    const int kh   = w >> 2;               // k-half 0..1
    const int lane = t & 63;
    const int d0   = nblk * DTILE;
    const int kbase = kblk * KPB + kh * 256;

    const int l15 = lane & 15;
    const int l4  = lane >> 4;
    const int dl  = lane >> 5;             // 0..1 : subspace within pair
    const int q   = lane & 31;             // 0..31 : k-pair within chunk

    // --- issue codebook stage loads (waves 0-3 only; 8 x b128 each)
    uint4 vst[8];
    if (kh == 0) {
        const size_t src0 = (size_t)(d0 + wp * 2) * KSQ;   // uint4 units
        #pragma unroll
        for (int p = 0; p < 8; ++p)
            vst[p] = vbf4[src0 + p * 64 + lane];
    }

    // --- issue ALL A-fragment loads (16 x b128) for this wave's 256-k half
    uint4 A[2][8];
    #pragma unroll
    for (int mt = 0; mt < 2; ++mt)
        #pragma unroll
        for (int kk = 0; kk < 8; ++kk)
            A[mt][kk] = *(const uint4*)
                &xbfu[(size_t)(mt * 16 + l15) * IN_DIM + kbase + kk * 32 + l4 * 8];

    // --- issue idx byte loads (4 x ushort)
    const uchar_t* idxrow = idx8T + (size_t)(d0 + wp * 2 + dl) * IN_DIM + kbase;
    uint_t bb[NCHUNK];
    #pragma unroll
    for (int c = 0; c < NCHUNK; ++c)
        bb[c] = *(const ushort_t*)&idxrow[c * KC + q * 2];

    // --- commit codebook to LDS (waits only the 8 stage loads; A/idx in flight)
    if (kh == 0) {
        #pragma unroll
        for (int p = 0; p < 8; ++p)
            sV4[wp * 512 + p * 64 + lane] = vst[p];
    }

    // --- pin A and idx in registers (opaque to the optimizer)
    #pragma unroll
    for (int mt = 0; mt < 2; ++mt)
        #pragma unroll
        for (int kk = 0; kk < 8; ++kk)
            pin4(A[mt][kk]);
    #pragma unroll
    for (int c = 0; c < NCHUNK; ++c)
        pin1(bb[c]);

    __builtin_amdgcn_sched_barrier(0);
    __syncthreads();                       // codebook visible to k-half-1 waves

    f32x4 acc[2];
    acc[0] = (f32x4)0.0f; acc[1] = (f32x4)0.0f;

    const int vbase = wp * 512 + dl * 256;
    const int Rbase = (w * 16 + dl * 8) * 32;   // dword base of this lane's 8 rows

    // prime gathers for chunk 0
    uint4 g0 = sV4[vbase + (bb[0] & 255)];
    uint4 g1 = sV4[vbase + (bb[0] >> 8)];

    #pragma unroll
    for (int c = 0; c < NCHUNK; ++c) {
        // transpose 2x8 -> 8 b32 writes; xor-swizzle 16B units with row (=j)
        #pragma unroll
        for (int j = 0; j < 8; ++j) {
            const uint_t sel = (j & 1) ? 0x07060302u : 0x05040100u;
            uint_t a0 = (j >> 1) == 0 ? g0.x : (j >> 1) == 1 ? g0.y : (j >> 1) == 2 ? g0.z : g0.w;
            uint_t a1 = (j >> 1) == 0 ? g1.x : (j >> 1) == 1 ? g1.y : (j >> 1) == 2 ? g1.z : g1.w;
            uint_t wv = __builtin_amdgcn_perm(a1, a0, sel);   // [k even | k odd<<16]
            int dw = ((((q >> 2) ^ j) << 2) | (q & 3));
            sW32[Rbase + j * 32 + dw] = wv;
        }

        // issue next chunk's gathers NOW: latency overlaps B-reads + MFMA
        uint4 n0 = g0, n1 = g1;
        if (c + 1 < NCHUNK) {
            n0 = sV4[vbase + (bb[c + 1] & 255)];
            n1 = sV4[vbase + (bb[c + 1] >> 8)];
        }

        // B read (swizzled) + MFMA
        #pragma unroll
        for (int kq = 0; kq < 2; ++kq) {
            int u16 = (kq * 4 + l4) ^ (l15 & 7);
            bf16x8 B = *(const bf16x8*)
                ((const char*)sW32 + (w * 16 + l15) * 128 + u16 * 16);
            #pragma unroll
            for (int mt = 0; mt < 2; ++mt)
                acc[mt] = __builtin_amdgcn_mfma_f32_16x16x32_bf16(
                    as_bf16x8(A[mt][c * 2 + kq]), B, acc[mt], 0, 0, 0);
        }
        g0 = n0; g1 = n1;
    }

    // --- dense store to this wave's k-slice slab (no atomics)
    const int ks = kblk * 2 + kh;          // 0..15
    float* sl = slab + (size_t)ks * BATCH * OUT_DIM;
    const int col = nblk * NTILE + wp * 16 + l15;
    #pragma unroll
    for (int mt = 0; mt < 2; ++mt)
        #pragma unroll
        for (int r = 0; r < 4; ++r)
            sl[(size_t)(mt * 16 + l4 * 4 + r) * OUT_DIM + col] = acc[mt][r];
}

// ---- reduce: out = bias + sum_k slabs -------------------------------------
__global__ __launch_bounds__(256) void pq_reduce(
    const float* __restrict__ slab, const float* __restrict__ bias,
    float* __restrict__ out)
{
    int i = blockIdx.x * 256 + threadIdx.x;        // < 88064
    int m = i / (OUT_DIM / 4), n4 = i - m * (OUT_DIM / 4);
    float4 s = ((const float4*)bias)[n4];
    #pragma unroll
    for (int kb = 0; kb < NSLICE; ++kb) {
        float4 v = ((const float4*)slab)[(size_t)(kb * BATCH + m) * (OUT_DIM / 4) + n4];
        s.x += v.x; s.y += v.y; s.z += v.z; s.w += v.w;
    }
    ((float4*)out)[(size_t)m * (OUT_DIM / 4) + n4] = s;
}

extern "C" void kernel_launch(void* const* d_in, const int* in_sizes, int n_in,
                              void* d_out, int out_size, void* d_ws, size_t ws_size,
                              hipStream_t stream) {
    const float* x    = (const float*)d_in[0];
    const float* vecs = (const float*)d_in[1];
    const float* bias = (const float*)d_in[2];
    const int*   idx  = (const int*)d_in[3];
    float* out = (float*)d_out;

    uint_t*  vbf   = (uint_t*)d_ws;
    uint_t*  xbf   = (uint_t*)((char*)d_ws + XBF_OFF);
    uchar_t* idx8T = (uchar_t*)((char*)d_ws + IDXT_OFF);
    float*   slab  = (float*)((char*)d_ws + SLAB_OFF);

    pq_prep<<<PACK_BLK + IDXT_BLK, 256, 0, stream>>>(x, vecs, idx, vbf, xbf, idx8T);
    pq_main<<<GRID_MAIN, 512, 0, stream>>>(
        (const ushort_t*)xbf, (const uint4*)vbf, idx8T, slab);
    pq_reduce<<<(BATCH * OUT_DIM / 4) / 256, 256, 0, stream>>>(slab, bias, out);
}

// Round 11
// 111.696 us; speedup vs baseline: 1.1751x; 1.1751x over previous
//
#include <hip/hip_runtime.h>

#define IN_DIM  4096
#define OUT_DIM 11008
#define NSUB    1376
#define KSQ     256
#define DSUB    8
#define BATCH   32

#define DTILE   8                    // subspaces per block
#define NTILE   64                   // output cols per block
#define KC      64                   // k per chunk
#define NTK     4                    // k-tiles per block
#define KPT     256                  // k per tile
#define NSLICE  4                    // slab k-slices (= k-groups)
#define NBLK    (OUT_DIM / NTILE)    // 172
#define NPX     22                   // nblk per XCD (8*22=176 padded)
#define GRID_MAIN (8 * NPX * NTK)    // 704 blocks: all-resident (<=3/CU)

typedef unsigned short ushort_t;
typedef unsigned int   uint_t;
typedef unsigned char  uchar_t;
typedef __attribute__((ext_vector_type(8))) short bf16x8;
typedef __attribute__((ext_vector_type(4))) float f32x4;

// workspace layout (bytes)
#define VEC_N    (NSUB * KSQ * DSUB)              // 2818048 floats
#define XBF_OFF  (VEC_N * 2)                      // 5636096  : xbf (bf16 x)
#define IDXT_OFF (XBF_OFF + BATCH * IN_DIM * 2)   // 5898240  : idx8T [NSUB][IN_DIM] u8
#define SLAB_OFF (IDXT_OFF + NSUB * IN_DIM)       // 11534336 : f32 slabs [NSLICE][BATCH][OUT_DIM]
#define PREP_V   (VEC_N / 2)                      // 1409024 uints (2 bf16 each)
#define PREP_X   (BATCH * IN_DIM / 2)             // 65536
#define PREP_N   (PREP_V + PREP_X)                // 1474560 = 5760 * 256
#define PACK_BLK (PREP_N / 256)                   // 5760
#define IDXT_BLK ((IN_DIM / 128) * (NSUB / 32))   // 1376

__device__ __forceinline__ ushort_t f2bf(float f) {
    union { float f; uint_t u; } a; a.f = f;
    uint_t u = a.u;
    u += 0x7fffu + ((u >> 16) & 1u);   // round-to-nearest-even
    return (ushort_t)(u >> 16);
}

// opaque register fence on scalar components (128-bit ties unsupported)
__device__ __forceinline__ void pin4(uint4& x) {
    asm volatile("" : "+v"(x.x), "+v"(x.y), "+v"(x.z), "+v"(x.w));
}
__device__ __forceinline__ void pin1(uint_t& x) { asm volatile("" : "+v"(x)); }
__device__ __forceinline__ bf16x8 as_bf16x8(uint4 u) {
    union { uint4 u; bf16x8 v; } c; c.u = u; return c.v;
}

// ---- prep: bf16-pack codebook + x, AND transpose idx -> u8 [d][k] ---------
__global__ __launch_bounds__(256) void pq_prep(
    const float* __restrict__ x, const float* __restrict__ vecs,
    const int* __restrict__ idx,
    uint_t* __restrict__ vbf, uint_t* __restrict__ xbf,
    uchar_t* __restrict__ idx8T)
{
    __shared__ uchar_t sT[32][144];
    const int t = threadIdx.x;

    if (blockIdx.x < PACK_BLK) {
        int tid = blockIdx.x * 256 + t;
        if (tid < PREP_V) {
            float2 v = ((const float2*)vecs)[tid];
            vbf[tid] = (uint_t)f2bf(v.x) | ((uint_t)f2bf(v.y) << 16);
        } else {
            int i = tid - PREP_V;
            float2 v = ((const float2*)x)[i];
            xbf[i] = (uint_t)f2bf(v.x) | ((uint_t)f2bf(v.y) << 16);
        }
        return;
    }

    // idx transpose path
    const int bid = blockIdx.x - PACK_BLK;
    const int k0 = (bid & 31) * 128, d0 = (bid >> 5) * 32;
    #pragma unroll
    for (int p = 0; p < 16; ++p) {
        int f = p * 256 + t;           // 0..4095
        int kk = f >> 5, dd = f & 31;
        sT[dd][kk] = (uchar_t)idx[(size_t)(k0 + kk) * NSUB + d0 + dd];
    }
    __syncthreads();
    int dd = t >> 3, seg = t & 7;
    uint4 v = *(const uint4*)&sT[dd][seg * 16];
    *(uint4*)&idx8T[(size_t)(d0 + dd) * IN_DIM + k0 + seg * 16] = v;
}

// ---- main: all-resident blocks, 4 k-tiles amortized per block -------------
//
// Grid = 704 blocks (172 nblk x 4 k-groups, XCD-grouped): <=3 blocks/CU with
// 4-resident LDS capacity -> EVERY block is resident from t=0, no sequential
// block rounds (the prior 2816-block grid had 11 slots/CU at 4-deep: ~3
// rounds of exposed prologue latency). Codebook staged ONCE per block (4x
// less stage traffic), K=1024 accumulated in registers across 4 tiles,
// slab slices 16 -> 4. Wave-local, barrier-free (R10 lesson: no coupling).
__global__ __launch_bounds__(256, 4) void pq_main(
    const ushort_t* __restrict__ xbfu, const uint4* __restrict__ vbf4,
    const uchar_t* __restrict__ idx8T, float* __restrict__ slab)
{
    __shared__ uint4  sV4[4 * 512];        // 32 KB: per-wave 2x256 codewords
    __shared__ uint_t sW32[4 * 16 * 32];   //  8 KB: per-wave 16 rows x 64 k (swizzled)

    const int id  = blockIdx.x;
    const int xcd = id & 7;
    const int s   = id >> 3;               // 0..87
    const int nl  = s % NPX;
    const int kg  = s / NPX;               // 0..3
    const int nblk = xcd * NPX + nl;
    if (nblk >= NBLK) return;

    const int t    = threadIdx.x;
    const int w    = t >> 6;
    const int lane = t & 63;
    const int d0   = nblk * DTILE;
    const int kbase = kg * (NTK * KPT);    // kg * 1024

    const int l15 = lane & 15;
    const int l4  = lane >> 4;
    const int dl  = lane >> 5;             // 0..1 : subspace within wave
    const int q   = lane & 31;             // 0..31 : k-pair within chunk

    // --- issue codebook stage loads (8 x b128, coalesced)
    uint4 vst[8];
    {
        const size_t src0 = (size_t)(d0 + w * 2) * KSQ;   // uint4 units
        #pragma unroll
        for (int p = 0; p < 8; ++p)
            vst[p] = vbf4[src0 + p * 64 + lane];
    }

    // --- issue ALL idx byte loads for the 4 tiles (16 x ushort)
    const uchar_t* idxrow = idx8T + (size_t)(d0 + w * 2 + dl) * IN_DIM + kbase;
    uint_t bb[NTK * 4];
    #pragma unroll
    for (int j = 0; j < NTK * 4; ++j)
        bb[j] = *(const ushort_t*)&idxrow[j * KC + q * 2];

    // --- issue tile-0 A-fragment loads (16 x b128)
    uint4 A[2][8];
    #pragma unroll
    for (int mt = 0; mt < 2; ++mt)
        #pragma unroll
        for (int kk = 0; kk < 8; ++kk)
            A[mt][kk] = *(const uint4*)
                &xbfu[(size_t)(mt * 16 + l15) * IN_DIM + kbase + kk * 32 + l4 * 8];

    // --- commit codebook to LDS (waits only the 8 stage loads; rest in flight)
    #pragma unroll
    for (int p = 0; p < 8; ++p)
        sV4[w * 512 + p * 64 + lane] = vst[p];

    // --- pin preloads (stop rematerialization into the loop)
    #pragma unroll
    for (int mt = 0; mt < 2; ++mt)
        #pragma unroll
        for (int kk = 0; kk < 8; ++kk)
            pin4(A[mt][kk]);
    #pragma unroll
    for (int j = 0; j < NTK * 4; ++j)
        pin1(bb[j]);

    __builtin_amdgcn_sched_barrier(0);

    f32x4 acc[2];
    acc[0] = (f32x4)0.0f; acc[1] = (f32x4)0.0f;

    const int vbase = w * 512 + dl * 256;
    const int Rbase = (w * 16 + dl * 8) * 32;   // dword base of this lane's 8 rows

    #pragma unroll
    for (int tile = 0; tile < NTK; ++tile) {
        // prime gathers for this tile's chunk 0
        uint4 g0 = sV4[vbase + (bb[tile * 4] & 255)];
        uint4 g1 = sV4[vbase + (bb[tile * 4] >> 8)];

        #pragma unroll
        for (int c = 0; c < 4; ++c) {
            // transpose 2x8 -> 8 b32 writes; xor-swizzle 16B units with row (=j)
            #pragma unroll
            for (int j = 0; j < 8; ++j) {
                const uint_t sel = (j & 1) ? 0x07060302u : 0x05040100u;
                uint_t a0 = (j >> 1) == 0 ? g0.x : (j >> 1) == 1 ? g0.y : (j >> 1) == 2 ? g0.z : g0.w;
                uint_t a1 = (j >> 1) == 0 ? g1.x : (j >> 1) == 1 ? g1.y : (j >> 1) == 2 ? g1.z : g1.w;
                uint_t wv = __builtin_amdgcn_perm(a1, a0, sel);   // [k even | k odd<<16]
                int dw = ((((q >> 2) ^ j) << 2) | (q & 3));
                sW32[Rbase + j * 32 + dw] = wv;
            }

            // issue next chunk's gathers NOW: latency overlaps B-reads + MFMA
            uint4 n0 = g0, n1 = g1;
            if (tile * 4 + c + 1 < NTK * 4) {
                n0 = sV4[vbase + (bb[tile * 4 + c + 1] & 255)];
                n1 = sV4[vbase + (bb[tile * 4 + c + 1] >> 8)];
            }

            // B read (swizzled) + MFMA
            #pragma unroll
            for (int kq = 0; kq < 2; ++kq) {
                int u16 = (kq * 4 + l4) ^ (l15 & 7);
                bf16x8 B = *(const bf16x8*)
                    ((const char*)sW32 + (w * 16 + l15) * 128 + u16 * 16);
                #pragma unroll
                for (int mt = 0; mt < 2; ++mt)
                    acc[mt] = __builtin_amdgcn_mfma_f32_16x16x32_bf16(
                        as_bf16x8(A[mt][c * 2 + kq]), B, acc[mt], 0, 0, 0);
            }
            g0 = n0; g1 = n1;
        }

        // load next tile's A fragments (16-wave TLP covers this latency)
        if (tile + 1 < NTK) {
            const int kt = kbase + (tile + 1) * KPT;
            #pragma unroll
            for (int mt = 0; mt < 2; ++mt)
                #pragma unroll
                for (int kk = 0; kk < 8; ++kk)
                    A[mt][kk] = *(const uint4*)
                        &xbfu[(size_t)(mt * 16 + l15) * IN_DIM + kt + kk * 32 + l4 * 8];
        }
    }

    // --- dense store to this k-group's slab (no atomics)
    float* sl = slab + (size_t)kg * BATCH * OUT_DIM;
    const int col = nblk * NTILE + w * 16 + l15;
    #pragma unroll
    for (int mt = 0; mt < 2; ++mt)
        #pragma unroll
        for (int r = 0; r < 4; ++r)
            sl[(size_t)(mt * 16 + l4 * 4 + r) * OUT_DIM + col] = acc[mt][r];
}

// ---- reduce: out = bias + sum_k slabs -------------------------------------
__global__ __launch_bounds__(256) void pq_reduce(
    const float* __restrict__ slab, const float* __restrict__ bias,
    float* __restrict__ out)
{
    int i = blockIdx.x * 256 + threadIdx.x;        // < 88064
    int m = i / (OUT_DIM / 4), n4 = i - m * (OUT_DIM / 4);
    float4 s = ((const float4*)bias)[n4];
    #pragma unroll
    for (int kb = 0; kb < NSLICE; ++kb) {
        float4 v = ((const float4*)slab)[(size_t)(kb * BATCH + m) * (OUT_DIM / 4) + n4];
        s.x += v.x; s.y += v.y; s.z += v.z; s.w += v.w;
    }
    ((float4*)out)[(size_t)m * (OUT_DIM / 4) + n4] = s;
}

extern "C" void kernel_launch(void* const* d_in, const int* in_sizes, int n_in,
                              void* d_out, int out_size, void* d_ws, size_t ws_size,
                              hipStream_t stream) {
    const float* x    = (const float*)d_in[0];
    const float* vecs = (const float*)d_in[1];
    const float* bias = (const float*)d_in[2];
    const int*   idx  = (const int*)d_in[3];
    float* out = (float*)d_out;

    uint_t*  vbf   = (uint_t*)d_ws;
    uint_t*  xbf   = (uint_t*)((char*)d_ws + XBF_OFF);
    uchar_t* idx8T = (uchar_t*)((char*)d_ws + IDXT_OFF);
    float*   slab  = (float*)((char*)d_ws + SLAB_OFF);

    pq_prep<<<PACK_BLK + IDXT_BLK, 256, 0, stream>>>(x, vecs, idx, vbf, xbf, idx8T);
    pq_main<<<GRID_MAIN, 256, 0, stream>>>(
        (const ushort_t*)xbf, (const uint4*)vbf, idx8T, slab);
    pq_reduce<<<(BATCH * OUT_DIM / 4) / 256, 256, 0, stream>>>(slab, bias, out);
}

// Round 12
// 96.594 us; speedup vs baseline: 1.3588x; 1.1563x over previous
//
#include <hip/hip_runtime.h>

#define IN_DIM  4096
#define OUT_DIM 11008
#define NSUB    1376
#define KSQ     256
#define DSUB    8
#define BATCH   32

#define DTILE   8                    // subspaces per block
#define NTILE   64                   // output cols per block
#define KC      64                   // k per chunk
#define NTK     4                    // k-tiles per block
#define KPT     256                  // k per tile
#define NSLICE  4                    // slab k-slices (= k-groups)
#define NBLK    (OUT_DIM / NTILE)    // 172
#define NPX     22                   // nblk per XCD (8*22=176 padded)
#define GRID_MAIN (8 * NPX * NTK)    // 704 blocks: all-resident (<=3/CU)

typedef unsigned short ushort_t;
typedef unsigned int   uint_t;
typedef unsigned char  uchar_t;
typedef __attribute__((ext_vector_type(8))) short bf16x8;
typedef __attribute__((ext_vector_type(4))) float f32x4;

// workspace layout (bytes)
#define VEC_N    (NSUB * KSQ * DSUB)              // 2818048 floats
#define XBF_OFF  (VEC_N * 2)                      // 5636096  : xfrag (bf16 x, fragment-tiled)
#define IDXT_OFF (XBF_OFF + BATCH * IN_DIM * 2)   // 5898240  : idx8T [NSUB][IN_DIM] u8
#define SLAB_OFF (IDXT_OFF + NSUB * IN_DIM)       // 11534336 : f32 slabs [NSLICE][BATCH][OUT_DIM]
#define PREP_V   (VEC_N / 2)                      // 1409024 uints (2 bf16 each)
#define PACK_VB  (PREP_V / 256)                   // 5504 blocks: vbf pack
#define PACK_XB  (BATCH * IN_DIM / 8 / 256)       // 64 blocks: xfrag pack
#define IDXT_BLK ((IN_DIM / 128) * (NSUB / 32))   // 1376 blocks: idx transpose
#define PREP_G   (PACK_VB + PACK_XB + IDXT_BLK)   // 6944

__device__ __forceinline__ ushort_t f2bf(float f) {
    union { float f; uint_t u; } a; a.f = f;
    uint_t u = a.u;
    u += 0x7fffu + ((u >> 16) & 1u);   // round-to-nearest-even
    return (ushort_t)(u >> 16);
}
__device__ __forceinline__ uint_t pack2(float lo, float hi) {
    return (uint_t)f2bf(lo) | ((uint_t)f2bf(hi) << 16);
}

// opaque register fence on scalar components (128-bit ties unsupported)
__device__ __forceinline__ void pin4(uint4& x) {
    asm volatile("" : "+v"(x.x), "+v"(x.y), "+v"(x.z), "+v"(x.w));
}
__device__ __forceinline__ void pin1(uint_t& x) { asm volatile("" : "+v"(x)); }
__device__ __forceinline__ bf16x8 as_bf16x8(uint4 u) {
    union { uint4 u; bf16x8 v; } c; c.u = u; return c.v;
}

// ---- prep: pack codebook; pack x into FRAGMENT-TILED layout; idx -> u8 ----
//
// xfrag element addr: f = (k>>5)*1024 + (row>>4)*512 + ((k>>3)&3)*128
//                       + (row&15)*8 + (k&7)
// so a wave's A-fragment load (mt,kblk) is 64 consecutive 16B units
// (lane = ((k>>3)&3)*16 + row&15) -> fully coalesced, 100% utilization.
// Old row-major layout: 16 separate 64B lines per b128 load, 25% used.
__global__ __launch_bounds__(256) void pq_prep(
    const float* __restrict__ x, const float* __restrict__ vecs,
    const int* __restrict__ idx,
    uint_t* __restrict__ vbf, uint4* __restrict__ xfrag4,
    uchar_t* __restrict__ idx8T)
{
    __shared__ uchar_t sT[32][144];
    const int t = threadIdx.x;

    if (blockIdx.x < PACK_VB) {
        int tid = blockIdx.x * 256 + t;
        float2 v = ((const float2*)vecs)[tid];
        vbf[tid] = pack2(v.x, v.y);
        return;
    }
    if (blockIdx.x < PACK_VB + PACK_XB) {
        int tid = (blockIdx.x - PACK_VB) * 256 + t;   // < 16384
        int row = tid >> 9, o = tid & 511;            // o = k-oct
        const float4* src = (const float4*)(x + (size_t)row * IN_DIM + o * 8);
        float4 v0 = src[0], v1 = src[1];
        uint4 u;
        u.x = pack2(v0.x, v0.y); u.y = pack2(v0.z, v0.w);
        u.z = pack2(v1.x, v1.y); u.w = pack2(v1.z, v1.w);
        xfrag4[(o >> 2) * 128 + (row >> 4) * 64 + (o & 3) * 16 + (row & 15)] = u;
        return;
    }

    // idx transpose path
    const int bid = blockIdx.x - (PACK_VB + PACK_XB);
    const int k0 = (bid & 31) * 128, d0 = (bid >> 5) * 32;
    #pragma unroll
    for (int p = 0; p < 16; ++p) {
        int f = p * 256 + t;           // 0..4095
        int kk = f >> 5, dd = f & 31;
        sT[dd][kk] = (uchar_t)idx[(size_t)(k0 + kk) * NSUB + d0 + dd];
    }
    __syncthreads();
    int dd = t >> 3, seg = t & 7;
    uint4 v = *(const uint4*)&sT[dd][seg * 16];
    *(uint4*)&idx8T[(size_t)(d0 + dd) * IN_DIM + k0 + seg * 16] = v;
}

// ---- main: all-resident blocks, coalesced fragment A-loads ----------------
//
// R11 structure (704 all-resident blocks, codebook staged once, K=1024 in
// registers, wave-local, barrier-free) + fragment-tiled A loads: each A b128
// is one fully-coalesced 16B/lane burst instead of 16 scattered 64B lines.
// A-path L2 transactions drop ~4x (2.9M -> 0.7M) -- the dominant residual
// per the R1-confirmed L2 transaction-throughput ceiling.
__global__ __launch_bounds__(256, 4) void pq_main(
    const uint4* __restrict__ xfrag4, const uint4* __restrict__ vbf4,
    const uchar_t* __restrict__ idx8T, float* __restrict__ slab)
{
    __shared__ uint4  sV4[4 * 512];        // 32 KB: per-wave 2x256 codewords
    __shared__ uint_t sW32[4 * 16 * 32];   //  8 KB: per-wave 16 rows x 64 k (swizzled)

    const int id  = blockIdx.x;
    const int xcd = id & 7;
    const int s   = id >> 3;               // 0..87
    const int nl  = s % NPX;
    const int kg  = s / NPX;               // 0..3
    const int nblk = xcd * NPX + nl;
    if (nblk >= NBLK) return;

    const int t    = threadIdx.x;
    const int w    = t >> 6;
    const int lane = t & 63;
    const int d0   = nblk * DTILE;
    const int kbase = kg * (NTK * KPT);    // kg * 1024

    const int l15 = lane & 15;
    const int l4  = lane >> 4;
    const int dl  = lane >> 5;             // 0..1 : subspace within wave
    const int q   = lane & 31;             // 0..31 : k-pair within chunk

    // --- issue codebook stage loads (8 x b128, coalesced)
    uint4 vst[8];
    {
        const size_t src0 = (size_t)(d0 + w * 2) * KSQ;   // uint4 units
        #pragma unroll
        for (int p = 0; p < 8; ++p)
            vst[p] = vbf4[src0 + p * 64 + lane];
    }

    // --- issue ALL idx byte loads for the 4 tiles (16 x ushort)
    const uchar_t* idxrow = idx8T + (size_t)(d0 + w * 2 + dl) * IN_DIM + kbase;
    uint_t bb[NTK * 4];
    #pragma unroll
    for (int j = 0; j < NTK * 4; ++j)
        bb[j] = *(const ushort_t*)&idxrow[j * KC + q * 2];

    // --- issue tile-0 A-fragment loads (16 x b128, fully coalesced)
    uint4 A[2][8];
    #pragma unroll
    for (int mt = 0; mt < 2; ++mt)
        #pragma unroll
        for (int kk = 0; kk < 8; ++kk)
            A[mt][kk] = xfrag4[((kbase >> 5) + kk) * 128 + mt * 64 + lane];

    // --- commit codebook to LDS (waits only the 8 stage loads; rest in flight)
    #pragma unroll
    for (int p = 0; p < 8; ++p)
        sV4[w * 512 + p * 64 + lane] = vst[p];

    // --- pin preloads (stop rematerialization into the loop)
    #pragma unroll
    for (int mt = 0; mt < 2; ++mt)
        #pragma unroll
        for (int kk = 0; kk < 8; ++kk)
            pin4(A[mt][kk]);
    #pragma unroll
    for (int j = 0; j < NTK * 4; ++j)
        pin1(bb[j]);

    __builtin_amdgcn_sched_barrier(0);

    f32x4 acc[2];
    acc[0] = (f32x4)0.0f; acc[1] = (f32x4)0.0f;

    const int vbase = w * 512 + dl * 256;
    const int Rbase = (w * 16 + dl * 8) * 32;   // dword base of this lane's 8 rows

    #pragma unroll
    for (int tile = 0; tile < NTK; ++tile) {
        // prime gathers for this tile's chunk 0
        uint4 g0 = sV4[vbase + (bb[tile * 4] & 255)];
        uint4 g1 = sV4[vbase + (bb[tile * 4] >> 8)];

        #pragma unroll
        for (int c = 0; c < 4; ++c) {
            // transpose 2x8 -> 8 b32 writes; xor-swizzle 16B units with row (=j)
            #pragma unroll
            for (int j = 0; j < 8; ++j) {
                const uint_t sel = (j & 1) ? 0x07060302u : 0x05040100u;
                uint_t a0 = (j >> 1) == 0 ? g0.x : (j >> 1) == 1 ? g0.y : (j >> 1) == 2 ? g0.z : g0.w;
                uint_t a1 = (j >> 1) == 0 ? g1.x : (j >> 1) == 1 ? g1.y : (j >> 1) == 2 ? g1.z : g1.w;
                uint_t wv = __builtin_amdgcn_perm(a1, a0, sel);   // [k even | k odd<<16]
                int dw = ((((q >> 2) ^ j) << 2) | (q & 3));
                sW32[Rbase + j * 32 + dw] = wv;
            }

            // issue next chunk's gathers NOW: latency overlaps B-reads + MFMA
            uint4 n0 = g0, n1 = g1;
            if (tile * 4 + c + 1 < NTK * 4) {
                n0 = sV4[vbase + (bb[tile * 4 + c + 1] & 255)];
                n1 = sV4[vbase + (bb[tile * 4 + c + 1] >> 8)];
            }

            // B read (swizzled) + MFMA
            #pragma unroll
            for (int kq = 0; kq < 2; ++kq) {
                int u16 = (kq * 4 + l4) ^ (l15 & 7);
                bf16x8 B = *(const bf16x8*)
                    ((const char*)sW32 + (w * 16 + l15) * 128 + u16 * 16);
                #pragma unroll
                for (int mt = 0; mt < 2; ++mt)
                    acc[mt] = __builtin_amdgcn_mfma_f32_16x16x32_bf16(
                        as_bf16x8(A[mt][c * 2 + kq]), B, acc[mt], 0, 0, 0);
            }
            g0 = n0; g1 = n1;
        }

        // load next tile's A fragments (coalesced; TLP covers the latency)
        if (tile + 1 < NTK) {
            const int kb5 = (kbase >> 5) + (tile + 1) * 8;
            #pragma unroll
            for (int mt = 0; mt < 2; ++mt)
                #pragma unroll
                for (int kk = 0; kk < 8; ++kk)
                    A[mt][kk] = xfrag4[(kb5 + kk) * 128 + mt * 64 + lane];
        }
    }

    // --- dense store to this k-group's slab (no atomics)
    float* sl = slab + (size_t)kg * BATCH * OUT_DIM;
    const int col = nblk * NTILE + w * 16 + l15;
    #pragma unroll
    for (int mt = 0; mt < 2; ++mt)
        #pragma unroll
        for (int r = 0; r < 4; ++r)
            sl[(size_t)(mt * 16 + l4 * 4 + r) * OUT_DIM + col] = acc[mt][r];
}

// ---- reduce: out = bias + sum_k slabs -------------------------------------
__global__ __launch_bounds__(256) void pq_reduce(
    const float* __restrict__ slab, const float* __restrict__ bias,
    float* __restrict__ out)
{
    int i = blockIdx.x * 256 + threadIdx.x;        // < 88064
    int m = i / (OUT_DIM / 4), n4 = i - m * (OUT_DIM / 4);
    float4 s = ((const float4*)bias)[n4];
    #pragma unroll
    for (int kb = 0; kb < NSLICE; ++kb) {
        float4 v = ((const float4*)slab)[(size_t)(kb * BATCH + m) * (OUT_DIM / 4) + n4];
        s.x += v.x; s.y += v.y; s.z += v.z; s.w += v.w;
    }
    ((float4*)out)[(size_t)m * (OUT_DIM / 4) + n4] = s;
}

extern "C" void kernel_launch(void* const* d_in, const int* in_sizes, int n_in,
                              void* d_out, int out_size, void* d_ws, size_t ws_size,
                              hipStream_t stream) {
    const float* x    = (const float*)d_in[0];
    const float* vecs = (const float*)d_in[1];
    const float* bias = (const float*)d_in[2];
    const int*   idx  = (const int*)d_in[3];
    float* out = (float*)d_out;

    uint_t*  vbf   = (uint_t*)d_ws;
    uint4*   xfrag = (uint4*)((char*)d_ws + XBF_OFF);
    uchar_t* idx8T = (uchar_t*)((char*)d_ws + IDXT_OFF);
    float*   slab  = (float*)((char*)d_ws + SLAB_OFF);

    pq_prep<<<PREP_G, 256, 0, stream>>>(x, vecs, idx, vbf, xfrag, idx8T);
    pq_main<<<GRID_MAIN, 256, 0, stream>>>(
        xfrag, (const uint4*)vbf, idx8T, slab);
    pq_reduce<<<(BATCH * OUT_DIM / 4) / 256, 256, 0, stream>>>(slab, bias, out);
}

// Round 13
// 96.386 us; speedup vs baseline: 1.3617x; 1.0022x over previous
//
#include <hip/hip_runtime.h>

#define IN_DIM  4096
#define OUT_DIM 11008
#define NSUB    1376
#define KSQ     256
#define DSUB    8
#define BATCH   32

#define DTILE   8                    // subspaces per block
#define NTILE   64                   // output cols per block
#define KC      64                   // k per chunk
#define NTK     4                    // k-tiles per block
#define KPT     256                  // k per tile
#define NSLICE  4                    // slab k-slices (= k-groups)
#define NBLK    (OUT_DIM / NTILE)    // 172
#define NPX     22                   // nblk per XCD (8*22=176 padded)
#define GRID_MAIN (8 * NPX * NTK)    // 704 blocks: all-resident (<=3/CU)

typedef unsigned short ushort_t;
typedef unsigned int   uint_t;
typedef unsigned char  uchar_t;
typedef __attribute__((ext_vector_type(8))) short bf16x8;
typedef __attribute__((ext_vector_type(4))) float f32x4;

// workspace layout (bytes) — vbf pass eliminated (main stages from f32)
#define XFRAG_OFF 0                               // xfrag bf16 [256 KB]
#define IDXT_OFF  (BATCH * IN_DIM * 2)            // 262144 : idx8T [NSUB][IN_DIM] u8
#define SLAB_OFF  (IDXT_OFF + NSUB * IN_DIM)      // 5898240: f32 slabs [NSLICE][BATCH][OUT_DIM]
#define PACK_XB  (BATCH * IN_DIM / 8 / 256)       // 64 blocks: xfrag pack
#define IDXT_BLK ((IN_DIM / 128) * (NSUB / 32))   // 1376 blocks: idx transpose
#define PREP_G   (PACK_XB + IDXT_BLK)             // 1440

__device__ __forceinline__ ushort_t f2bf(float f) {
    union { float f; uint_t u; } a; a.f = f;
    uint_t u = a.u;
    u += 0x7fffu + ((u >> 16) & 1u);   // round-to-nearest-even
    return (ushort_t)(u >> 16);
}
__device__ __forceinline__ uint_t pack2(float lo, float hi) {
    return (uint_t)f2bf(lo) | ((uint_t)f2bf(hi) << 16);
}

// opaque register fence on scalar components (128-bit ties unsupported)
__device__ __forceinline__ void pin4(uint4& x) {
    asm volatile("" : "+v"(x.x), "+v"(x.y), "+v"(x.z), "+v"(x.w));
}
__device__ __forceinline__ void pin1(uint_t& x) { asm volatile("" : "+v"(x)); }
__device__ __forceinline__ bf16x8 as_bf16x8(uint4 u) {
    union { uint4 u; bf16x8 v; } c; c.u = u; return c.v;
}

// ---- prep: pack x into FRAGMENT-TILED bf16 layout; transpose idx -> u8 ----
//
// xfrag element addr: f = (k>>5)*1024 + (row>>4)*512 + ((k>>3)&3)*128
//                       + (row&15)*8 + (k&7)
// so a wave's A-fragment load (mt,kblk) is 64 consecutive 16B units ->
// fully coalesced, 100% line utilization (R12: -15 us, confirmed).
__global__ __launch_bounds__(256) void pq_prep(
    const float* __restrict__ x, const int* __restrict__ idx,
    uint4* __restrict__ xfrag4, uchar_t* __restrict__ idx8T)
{
    __shared__ uchar_t sT[32][144];
    const int t = threadIdx.x;

    if (blockIdx.x < PACK_XB) {
        int tid = blockIdx.x * 256 + t;               // < 16384
        int row = tid >> 9, o = tid & 511;            // o = k-oct
        const float4* src = (const float4*)(x + (size_t)row * IN_DIM + o * 8);
        float4 v0 = src[0], v1 = src[1];
        uint4 u;
        u.x = pack2(v0.x, v0.y); u.y = pack2(v0.z, v0.w);
        u.z = pack2(v1.x, v1.y); u.w = pack2(v1.z, v1.w);
        xfrag4[(o >> 2) * 128 + (row >> 4) * 64 + (o & 3) * 16 + (row & 15)] = u;
        return;
    }

    // idx transpose path
    const int bid = blockIdx.x - PACK_XB;
    const int k0 = (bid & 31) * 128, d0 = (bid >> 5) * 32;
    #pragma unroll
    for (int p = 0; p < 16; ++p) {
        int f = p * 256 + t;           // 0..4095
        int kk = f >> 5, dd = f & 31;
        sT[dd][kk] = (uchar_t)idx[(size_t)(k0 + kk) * NSUB + d0 + dd];
    }
    __syncthreads();
    int dd = t >> 3, seg = t & 7;
    uint4 v = *(const uint4*)&sT[dd][seg * 16];
    *(uint4*)&idx8T[(size_t)(d0 + dd) * IN_DIM + k0 + seg * 16] = v;
}

// ---- main: all-resident blocks; codebook staged from f32 directly ---------
//
// R12 structure (704 all-resident blocks, K=1024 in registers, wave-local,
// barrier-free, fragment-tiled coalesced A loads) + codebook staged straight
// from f32 vecs with in-register bf16 pack: kills the 5504-block vbf prep
// pass (17 MB HBM round trip). Stage VALU (~64 ops/thread, once per block)
// hides under the in-flight A/idx loads. XCD-grouped: the 4 k-group blocks
// of an nblk share the same XCD's L2 for the f32 slice re-read.
__global__ __launch_bounds__(256, 4) void pq_main(
    const uint4* __restrict__ xfrag4, const float4* __restrict__ vf4,
    const uchar_t* __restrict__ idx8T, float* __restrict__ slab)
{
    __shared__ uint4  sV4[4 * 512];        // 32 KB: per-wave 2x256 codewords (bf16)
    __shared__ uint_t sW32[4 * 16 * 32];   //  8 KB: per-wave 16 rows x 64 k (swizzled)

    const int id  = blockIdx.x;
    const int xcd = id & 7;
    const int s   = id >> 3;               // 0..87
    const int nl  = s % NPX;
    const int kg  = s / NPX;               // 0..3
    const int nblk = xcd * NPX + nl;
    if (nblk >= NBLK) return;

    const int t    = threadIdx.x;
    const int w    = t >> 6;
    const int lane = t & 63;
    const int d0   = nblk * DTILE;
    const int kbase = kg * (NTK * KPT);    // kg * 1024

    const int l15 = lane & 15;
    const int l4  = lane >> 4;
    const int dl  = lane >> 5;             // 0..1 : subspace within wave
    const int q   = lane & 31;             // 0..31 : k-pair within chunk

    // --- issue codebook stage loads from f32 (16 x float4, coalesced pairs)
    float4 vs0[8], vs1[8];
    {
        const float4* src = vf4 + (size_t)(d0 + w * 2) * (KSQ * 2);  // float4 units
        #pragma unroll
        for (int p = 0; p < 8; ++p) {
            vs0[p] = src[(p * 64 + lane) * 2];
            vs1[p] = src[(p * 64 + lane) * 2 + 1];
        }
    }

    // --- issue ALL idx byte loads for the 4 tiles (16 x ushort)
    const uchar_t* idxrow = idx8T + (size_t)(d0 + w * 2 + dl) * IN_DIM + kbase;
    uint_t bb[NTK * 4];
    #pragma unroll
    for (int j = 0; j < NTK * 4; ++j)
        bb[j] = *(const ushort_t*)&idxrow[j * KC + q * 2];

    // --- issue tile-0 A-fragment loads (16 x b128, fully coalesced)
    uint4 A[2][8];
    #pragma unroll
    for (int mt = 0; mt < 2; ++mt)
        #pragma unroll
        for (int kk = 0; kk < 8; ++kk)
            A[mt][kk] = xfrag4[((kbase >> 5) + kk) * 128 + mt * 64 + lane];

    // --- pack + commit codebook to LDS (waits only the 16 stage loads)
    #pragma unroll
    for (int p = 0; p < 8; ++p) {
        uint4 o;
        o.x = pack2(vs0[p].x, vs0[p].y); o.y = pack2(vs0[p].z, vs0[p].w);
        o.z = pack2(vs1[p].x, vs1[p].y); o.w = pack2(vs1[p].z, vs1[p].w);
        sV4[w * 512 + p * 64 + lane] = o;
    }

    // --- pin preloads (stop rematerialization into the loop)
    #pragma unroll
    for (int mt = 0; mt < 2; ++mt)
        #pragma unroll
        for (int kk = 0; kk < 8; ++kk)
            pin4(A[mt][kk]);
    #pragma unroll
    for (int j = 0; j < NTK * 4; ++j)
        pin1(bb[j]);

    __builtin_amdgcn_sched_barrier(0);

    f32x4 acc[2];
    acc[0] = (f32x4)0.0f; acc[1] = (f32x4)0.0f;

    const int vbase = w * 512 + dl * 256;
    const int Rbase = (w * 16 + dl * 8) * 32;   // dword base of this lane's 8 rows

    #pragma unroll
    for (int tile = 0; tile < NTK; ++tile) {
        // prime gathers for this tile's chunk 0
        uint4 g0 = sV4[vbase + (bb[tile * 4] & 255)];
        uint4 g1 = sV4[vbase + (bb[tile * 4] >> 8)];

        #pragma unroll
        for (int c = 0; c < 4; ++c) {
            // transpose 2x8 -> 8 b32 writes; xor-swizzle 16B units with row (=j)
            #pragma unroll
            for (int j = 0; j < 8; ++j) {
                const uint_t sel = (j & 1) ? 0x07060302u : 0x05040100u;
                uint_t a0 = (j >> 1) == 0 ? g0.x : (j >> 1) == 1 ? g0.y : (j >> 1) == 2 ? g0.z : g0.w;
                uint_t a1 = (j >> 1) == 0 ? g1.x : (j >> 1) == 1 ? g1.y : (j >> 1) == 2 ? g1.z : g1.w;
                uint_t wv = __builtin_amdgcn_perm(a1, a0, sel);   // [k even | k odd<<16]
                int dw = ((((q >> 2) ^ j) << 2) | (q & 3));
                sW32[Rbase + j * 32 + dw] = wv;
            }

            // issue next chunk's gathers NOW: latency overlaps B-reads + MFMA
            uint4 n0 = g0, n1 = g1;
            if (tile * 4 + c + 1 < NTK * 4) {
                n0 = sV4[vbase + (bb[tile * 4 + c + 1] & 255)];
                n1 = sV4[vbase + (bb[tile * 4 + c + 1] >> 8)];
            }

            // B read (swizzled) + MFMA
            #pragma unroll
            for (int kq = 0; kq < 2; ++kq) {
                int u16 = (kq * 4 + l4) ^ (l15 & 7);
                bf16x8 B = *(const bf16x8*)
                    ((const char*)sW32 + (w * 16 + l15) * 128 + u16 * 16);
                #pragma unroll
                for (int mt = 0; mt < 2; ++mt)
                    acc[mt] = __builtin_amdgcn_mfma_f32_16x16x32_bf16(
                        as_bf16x8(A[mt][c * 2 + kq]), B, acc[mt], 0, 0, 0);
            }
            g0 = n0; g1 = n1;
        }

        // load next tile's A fragments (coalesced; TLP covers the latency)
        if (tile + 1 < NTK) {
            const int kb5 = (kbase >> 5) + (tile + 1) * 8;
            #pragma unroll
            for (int mt = 0; mt < 2; ++mt)
                #pragma unroll
                for (int kk = 0; kk < 8; ++kk)
                    A[mt][kk] = xfrag4[(kb5 + kk) * 128 + mt * 64 + lane];
        }
    }

    // --- dense store to this k-group's slab (no atomics)
    float* sl = slab + (size_t)kg * BATCH * OUT_DIM;
    const int col = nblk * NTILE + w * 16 + l15;
    #pragma unroll
    for (int mt = 0; mt < 2; ++mt)
        #pragma unroll
        for (int r = 0; r < 4; ++r)
            sl[(size_t)(mt * 16 + l4 * 4 + r) * OUT_DIM + col] = acc[mt][r];
}

// ---- reduce: out = bias + sum_k slabs -------------------------------------
__global__ __launch_bounds__(256) void pq_reduce(
    const float* __restrict__ slab, const float* __restrict__ bias,
    float* __restrict__ out)
{
    int i = blockIdx.x * 256 + threadIdx.x;        // < 88064
    int m = i / (OUT_DIM / 4), n4 = i - m * (OUT_DIM / 4);
    float4 s = ((const float4*)bias)[n4];
    #pragma unroll
    for (int kb = 0; kb < NSLICE; ++kb) {
        float4 v = ((const float4*)slab)[(size_t)(kb * BATCH + m) * (OUT_DIM / 4) + n4];
        s.x += v.x; s.y += v.y; s.z += v.z; s.w += v.w;
    }
    ((float4*)out)[(size_t)m * (OUT_DIM / 4) + n4] = s;
}

extern "C" void kernel_launch(void* const* d_in, const int* in_sizes, int n_in,
                              void* d_out, int out_size, void* d_ws, size_t ws_size,
                              hipStream_t stream) {
    const float* x    = (const float*)d_in[0];
    const float* vecs = (const float*)d_in[1];
    const float* bias = (const float*)d_in[2];
    const int*   idx  = (const int*)d_in[3];
    float* out = (float*)d_out;

    uint4*   xfrag = (uint4*)((char*)d_ws + XFRAG_OFF);
    uchar_t* idx8T = (uchar_t*)((char*)d_ws + IDXT_OFF);
    float*   slab  = (float*)((char*)d_ws + SLAB_OFF);

    pq_prep<<<PREP_G, 256, 0, stream>>>(x, idx, xfrag, idx8T);
    pq_main<<<GRID_MAIN, 256, 0, stream>>>(
        xfrag, (const float4*)vecs, idx8T, slab);
    pq_reduce<<<(BATCH * OUT_DIM / 4) / 256, 256, 0, stream>>>(slab, bias, out);
}